// Round 2
// baseline (2045.944 us; speedup 1.0000x reference)
//
#include <hip/hip_runtime.h>
#include <stdint.h>

typedef unsigned short u16;
typedef __attribute__((ext_vector_type(8))) short bfrag;   // 8 x bf16 (4 VGPR)
typedef __attribute__((ext_vector_type(4))) float f32x4;   // MFMA accumulator

#define MFMA16(a,b,c) __builtin_amdgcn_mfma_f32_16x16x32_bf16(a,b,c,0,0,0)

__device__ __forceinline__ u16 f2b(float f){
  union { float f; uint32_t u; } v; v.f = f;
  uint32_t r = v.u + 0x7FFFu + ((v.u >> 16) & 1u);   // RNE, finite-only
  return (u16)(r >> 16);
}
__device__ __forceinline__ u16 f2b_fast(float f){    // round-half-up (P only)
  union { float f; uint32_t u; } v; v.f = f;
  return (u16)((v.u + 0x8000u) >> 16);
}
__device__ __forceinline__ float b2f(u16 b){
  union { uint32_t u; float f; } v; v.u = ((uint32_t)b) << 16; return v.f;
}

typedef const __attribute__((address_space(1))) unsigned int* gas_t;
typedef __attribute__((address_space(3))) unsigned int* las_t;
__device__ __forceinline__ void async16(const u16* g, u16* l){
  __builtin_amdgcn_global_load_lds((gas_t)g, (las_t)l, 16, 0, 0);
}

// ---------------- elementwise conversions ----------------
__global__ __launch_bounds__(256) void cvt_x_k(const float* __restrict__ x, u16* __restrict__ o, int n){
  int i = blockIdx.x*256 + threadIdx.x;
  if (i < n) o[i] = f2b(x[i]);
}
__global__ __launch_bounds__(256) void eot_k(const float* __restrict__ eot, float* __restrict__ hF, u16* __restrict__ hbf){
  int i = blockIdx.x*256 + threadIdx.x;          // [32 b][512 d]
  int b = i >> 9, d = i & 511;
  float v = eot[d];
  size_t idx = ((size_t)b*513 + 512)*512 + d;
  hF[idx] = v; hbf[idx] = f2b(v);
}

// ---------------- tiled transpose + convert ----------------
// src slice: src + (s/div)*srcA + (s%div)*srcB, row stride SS, shape R x C (C%64==0)
// dst slice: dst + (s/div)*dstA + (s%div)*dstB, row stride DS; out[c][r] = src[r][c]
template<typename T>
__global__ __launch_bounds__(256) void trans_k(const T* __restrict__ src, u16* __restrict__ dst,
    int R, int C, int SS, int DS, int div, size_t srcA, size_t srcB, size_t dstA, size_t dstB)
{
  __shared__ u16 tile[64][72];
  int s = blockIdx.z;
  const T* sp = src + (size_t)(s/div)*srcA + (size_t)(s%div)*srcB;
  u16* dp = dst + (size_t)(s/div)*dstA + (size_t)(s%div)*dstB;
  int r0 = blockIdx.x*64, c0 = blockIdx.y*64;
  int t = threadIdx.x;
  int tr = t>>2, tc = (t&3)*16;
  int rr = r0+tr; if (rr >= R) rr = R-1;
  const T* p = sp + (size_t)rr*SS + c0 + tc;
  u16 bv[16];
  if constexpr (sizeof(T)==4) {
    float4 a = *(const float4*)p, b = *(const float4*)(p+4),
           c = *(const float4*)(p+8), d = *(const float4*)(p+12);
    float f[16] = {a.x,a.y,a.z,a.w,b.x,b.y,b.z,b.w,c.x,c.y,c.z,c.w,d.x,d.y,d.z,d.w};
    #pragma unroll
    for (int i=0;i<16;i++) bv[i] = f2b(f[i]);
  } else {
    *(uint4*)&bv[0] = ((const uint4*)p)[0];
    *(uint4*)&bv[8] = ((const uint4*)p)[1];
  }
  *(uint4*)&tile[tr][tc]   = *(uint4*)&bv[0];
  *(uint4*)&tile[tr][tc+8] = *(uint4*)&bv[8];
  __syncthreads();
  int oc = t>>2, orr = (t&3)*16;
  u16 ov[16];
  #pragma unroll
  for (int i=0;i<16;i++) ov[i] = tile[orr+i][oc];
  u16* q = dp + (size_t)(c0+oc)*DS + r0 + orr;
  if (r0 + 64 <= R) {
    *(uint4*)q     = *(uint4*)&ov[0];
    *(uint4*)(q+8) = *(uint4*)&ov[8];
  } else {
    #pragma unroll
    for (int i=0;i<16;i++){
      int rg = r0 + orr + i;
      if (rg < DS) q[i] = (rg < R) ? ov[i] : (u16)0;   // zero-fill pad cols (finite bf16)
    }
  }
}

// ---------------- GEMM: C[M,N] = A[M,K](bf16) * BT[N,K](bf16)^T, BK=64 ----------------
// LDS[row][ch] holds global chunk (ch ^ (row&7)); frag chunk c read at ch = c^(rr&7)
template<bool BIAS,bool RELU,bool SKIP,bool OUTF,bool OUTB,bool REMAP>
__global__ __launch_bounds__(256,2) void gemm_k(
    const u16* __restrict__ A, const u16* __restrict__ BT,
    const float* __restrict__ bias, const float* __restrict__ skip,
    float* __restrict__ outF, u16* __restrict__ outB,
    int M, int N, int K)
{
  __shared__ u16 Ash[128*64];
  __shared__ u16 Bsh[128*64];
  const int tid = threadIdx.x;
  const int lane = tid & 63, wv = tid >> 6;
  const int mt = blockIdx.x, nt = blockIdx.y;
  const int wrow = (wv >> 1) << 6, wcol = (wv & 1) << 6;
  const int g = lane >> 4, ci = lane & 15;

  f32x4 acc[4][4];
  #pragma unroll
  for (int i=0;i<4;i++)
    #pragma unroll
    for (int j=0;j<4;j++) acc[i][j] = (f32x4){0.f,0.f,0.f,0.f};

  int aofs[4][2], bofs[4][2];
  #pragma unroll
  for (int mi=0;mi<4;mi++){
    int rr = wrow + mi*16 + ci;
    int cc = wcol + mi*16 + ci;
    #pragma unroll
    for (int kh=0;kh<2;kh++){
      aofs[mi][kh] = rr*64 + ((((kh<<2)|g) ^ (rr&7))<<3);
      bofs[mi][kh] = cc*64 + ((((kh<<2)|g) ^ (cc&7))<<3);
    }
  }
  const u16* ga[4]; const u16* gb[4];
  #pragma unroll
  for (int q=0;q<4;q++){
    int row = q*32 + (tid>>3);
    int sc  = (tid&7) ^ (row&7);
    int arow = mt*128 + row; if (arow >= M) arow = M-1;
    int brow = nt*128 + row;
    ga[q] = A  + (size_t)arow*K + sc*8;
    gb[q] = BT + (size_t)brow*K + sc*8;
  }
  u16* la = Ash + tid*8;
  u16* lb = Bsh + tid*8;

  for (int kt = 0; kt < K; kt += 64){
    #pragma unroll
    for (int q=0;q<4;q++) async16(ga[q] + kt, la + q*2048);
    #pragma unroll
    for (int q=0;q<4;q++) async16(gb[q] + kt, lb + q*2048);
    __syncthreads();
    #pragma unroll
    for (int kh=0;kh<2;kh++){
      bfrag a[4], b[4];
      #pragma unroll
      for (int mi=0;mi<4;mi++) a[mi] = *(const bfrag*)&Ash[aofs[mi][kh]];
      #pragma unroll
      for (int ni=0;ni<4;ni++) b[ni] = *(const bfrag*)&Bsh[bofs[ni][kh]];
      #pragma unroll
      for (int mi=0;mi<4;mi++)
        #pragma unroll
        for (int ni=0;ni<4;ni++)
          acc[mi][ni] = MFMA16(a[mi], b[ni], acc[mi][ni]);
    }
    __syncthreads();
  }

  #pragma unroll
  for (int mi=0;mi<4;mi++){
    #pragma unroll
    for (int r=0;r<4;r++){
      int gm = mt*128 + wrow + mi*16 + g*4 + r;
      if (gm >= M) continue;
      size_t orow = REMAP ? (size_t)(gm + (gm >> 9)) : (size_t)gm;
      #pragma unroll
      for (int ni=0;ni<4;ni++){
        int gn = nt*128 + wcol + ni*16 + ci;
        float v = acc[mi][ni][r];
        if (BIAS) v += bias[gn];
        if (SKIP) v += skip[(size_t)gm*N + gn];
        if (RELU) v = fmaxf(v, 0.f);
        if (OUTF) outF[orow*N + gn] = v;
        if (OUTB) outB[orow*N + gn] = f2b(v);
      }
    }
  }
}

// ---------------- attention: 4 waves/block, wave = one 16-row q-tile, KVB=64 ----------------
// qkv rows [b*513+n][1536] = Q|K|V each h*64+d ; Vt [b*8+h][64 d][520 n] bf16
#define LOG2E_SC 0.1803368801f   /* 0.125 * log2(e) */
__global__ __launch_bounds__(256) void attn_k(const u16* __restrict__ qkv, const u16* __restrict__ Vt,
                                              u16* __restrict__ heads)
{
  __shared__ u16 P_lds[4][16*72];
  const int wv = threadIdx.x >> 6;
  const int qt = blockIdx.x*4 + wv;
  if (qt > 32) return;
  const int b = blockIdx.y, hh = blockIdx.z;
  const int lane = threadIdx.x & 63;
  const int g = lane >> 4, ci = lane & 15;
  u16* P_l = P_lds[wv];

  const size_t rowb = (size_t)b * 513;
  int q = qt*16 + ci; int qr = q < 513 ? q : 512;
  const u16* qp = qkv + (rowb + qr)*1536 + hh*64 + g*8;
  bfrag aq0 = *(const bfrag*)qp;
  bfrag aq1 = *(const bfrag*)(qp + 32);

  const u16* kbase = qkv + rowb*1536 + 512 + hh*64;
  const u16* vbase = Vt + (size_t)(b*8 + hh)*33280;

  f32x4 hacc[4];
  #pragma unroll
  for (int dt=0;dt<4;dt++) hacc[dt] = (f32x4){0.f,0.f,0.f,0.f};
  float mrun[4] = {-1e30f,-1e30f,-1e30f,-1e30f};
  float srun[4] = {0.f,0.f,0.f,0.f};

  for (int np = 0; np < 9; ++np){
    const int n0 = np*64;
    const bool tail = (np == 8);
    // K fragments (8 x b128 global)
    bfrag kf[4][2];
    #pragma unroll
    for (int t=0;t<4;t++){
      int n = n0 + t*16 + ci; if (n > 512) n = 512;
      const u16* kp = kbase + (size_t)n*1536;
      kf[t][0] = *(const bfrag*)(kp + g*8);
      kf[t][1] = *(const bfrag*)(kp + 32 + g*8);
    }
    // V fragments (8 x b128 global from Vt rows)
    bfrag vf[4][2];
    #pragma unroll
    for (int dt=0;dt<4;dt++){
      const u16* vr = vbase + (size_t)(dt*16 + ci)*520;
      #pragma unroll
      for (int kh=0;kh<2;kh++){
        int nv = tail ? 512 : (n0 + kh*32 + g*8);
        vf[dt][kh] = *(const bfrag*)(vr + nv);
      }
    }
    // S = Q K^T, scaled into log2 domain
    f32x4 s[4];
    #pragma unroll
    for (int t=0;t<4;t++){
      f32x4 z = (f32x4){0.f,0.f,0.f,0.f};
      z = MFMA16(aq0, kf[t][0], z);
      z = MFMA16(aq1, kf[t][1], z);
      #pragma unroll
      for (int r=0;r<4;r++) s[t][r] = z[r]*LOG2E_SC;
    }
    if (tail){
      #pragma unroll
      for (int t=0;t<4;t++){
        bool v = (n0 + t*16 + ci) < 513;
        #pragma unroll
        for (int r=0;r<4;r++) s[t][r] = v ? s[t][r] : -1e30f;
      }
    }
    // online softmax: row = g*4+r, reduce over n = t*16+ci
    float pm[4];
    #pragma unroll
    for (int r=0;r<4;r++)
      pm[r] = fmaxf(fmaxf(s[0][r],s[1][r]), fmaxf(s[2][r],s[3][r]));
    #pragma unroll
    for (int m=1;m<16;m<<=1)
      #pragma unroll
      for (int r=0;r<4;r++) pm[r] = fmaxf(pm[r], __shfl_xor(pm[r], m));
    float f[4];
    #pragma unroll
    for (int r=0;r<4;r++){
      float mn = fmaxf(mrun[r], pm[r]);
      f[r] = __builtin_exp2f(mrun[r] - mn);
      mrun[r] = mn;
      #pragma unroll
      for (int t=0;t<4;t++) s[t][r] = __builtin_exp2f(s[t][r] - mn);
    }
    float psum[4];
    #pragma unroll
    for (int r=0;r<4;r++) psum[r] = (s[0][r]+s[1][r]) + (s[2][r]+s[3][r]);
    #pragma unroll
    for (int m=1;m<16;m<<=1)
      #pragma unroll
      for (int r=0;r<4;r++) psum[r] += __shfl_xor(psum[r], m);
    #pragma unroll
    for (int r=0;r<4;r++) srun[r] = srun[r]*f[r] + psum[r];
    #pragma unroll
    for (int dt=0;dt<4;dt++){
      hacc[dt][0]*=f[0]; hacc[dt][1]*=f[1]; hacc[dt][2]*=f[2]; hacc[dt][3]*=f[3];
    }
    // P -> LDS (row q=g*4+r, col n-local = t*16+ci)
    #pragma unroll
    for (int r=0;r<4;r++)
      #pragma unroll
      for (int t=0;t<4;t++)
        P_l[(g*4+r)*72 + t*16 + ci] = f2b_fast(s[t][r]);
    // A-frag: row = ci, k = kh*32 + g*8 + j  (same-wave DS ordering; compiler inserts waits)
    bfrag pa0 = *(const bfrag*)&P_l[ci*72 + g*8];
    bfrag pa1 = *(const bfrag*)&P_l[ci*72 + 32 + g*8];
    #pragma unroll
    for (int dt=0;dt<4;dt++){
      hacc[dt] = MFMA16(pa0, vf[dt][0], hacc[dt]);
      hacc[dt] = MFMA16(pa1, vf[dt][1], hacc[dt]);
    }
  }
  float rs[4];
  #pragma unroll
  for (int r=0;r<4;r++) rs[r] = 1.0f / srun[r];
  #pragma unroll
  for (int dt=0;dt<4;dt++)
    #pragma unroll
    for (int r=0;r<4;r++){
      int qg = qt*16 + g*4 + r;
      if (qg < 513)
        heads[(rowb + qg)*512 + hh*64 + dt*16 + ci] = f2b(hacc[dt][r]*rs[r]);
    }
}

// ---------------- BatchNorm (train-mode, biased var) ----------------
#define NB 1026
__global__ __launch_bounds__(256) void bn_stats_k(const float* __restrict__ in, float* __restrict__ p1, float* __restrict__ p2){
  int blk = blockIdx.x, t = threadIdx.x;       // grid 513, rows blk*32..+31
  int c4 = t & 127, rh = t >> 7;
  float4 s = {0,0,0,0}, qq = {0,0,0,0};
  for (int i = rh; i < 32; i += 2){
    float4 v = ((const float4*)in)[(size_t)(blk*32 + i)*128 + c4];
    s.x += v.x; s.y += v.y; s.z += v.z; s.w += v.w;
    qq.x += v.x*v.x; qq.y += v.y*v.y; qq.z += v.z*v.z; qq.w += v.w*v.w;
  }
  size_t base = (size_t)(c4*4)*NB + blk*2 + rh;
  p1[base] = s.x; p1[base+NB] = s.y; p1[base+2*NB] = s.z; p1[base+3*NB] = s.w;
  p2[base] = qq.x; p2[base+NB] = qq.y; p2[base+2*NB] = qq.z; p2[base+3*NB] = qq.w;
}
__global__ __launch_bounds__(256) void bn_fin_k(const float* __restrict__ p1, const float* __restrict__ p2,
                                               const float* __restrict__ gamma, const float* __restrict__ beta,
                                               float2* __restrict__ sc){
  int c = blockIdx.x*256 + threadIdx.x;   // 2 blocks -> 512 channels
  float S=0.f,Q=0.f;
  for (int i=0;i<NB;i++){ S += p1[(size_t)c*NB+i]; Q += p2[(size_t)c*NB+i]; }
  const float invM = 1.0f/16416.0f;
  float mean = S*invM;
  float var  = Q*invM - mean*mean;
  float scl  = gamma[c] * rsqrtf(var + 1e-5f);
  sc[c] = make_float2(scl, beta[c] - mean*scl);
}
__global__ __launch_bounds__(256) void bn_apply_k(const float* __restrict__ in, const float2* __restrict__ sc,
                                                  float* __restrict__ outF, u16* __restrict__ outB){
  const int n4 = 16416*512/4;
  for (int i = blockIdx.x*256 + threadIdx.x; i < n4; i += gridDim.x*256){
    float4 v = ((const float4*)in)[i];
    int c0 = (i << 2) & 511;
    float2 a = sc[c0], b = sc[c0+1], c = sc[c0+2], d = sc[c0+3];
    v.x = v.x*a.x + a.y; v.y = v.y*b.x + b.y; v.z = v.z*c.x + c.y; v.w = v.w*d.x + d.y;
    ((float4*)outF)[i] = v;
    ushort4 u; u.x=f2b(v.x); u.y=f2b(v.y); u.z=f2b(v.z); u.w=f2b(v.w);
    ((ushort4*)outB)[i] = u;
  }
}

// ---------------- host launcher ----------------
static inline size_t alignup(size_t x){ return (x + 255) & ~(size_t)255; }

extern "C" void kernel_launch(void* const* d_in, const int* in_sizes, int n_in,
                              void* d_out, int out_size, void* d_ws, size_t ws_size,
                              hipStream_t stream)
{
  (void)in_sizes; (void)n_in; (void)out_size; (void)ws_size;
  const float* x      = (const float*)d_in[0];
  const float* W_init = (const float*)d_in[1];
  const float* b_init = (const float*)d_in[2];
  const float* eot    = (const float*)d_in[3];
  const float* Wq     = (const float*)d_in[4];
  const float* Wk     = (const float*)d_in[5];
  const float* Wv     = (const float*)d_in[6];
  const float* Wo     = (const float*)d_in[7];
  const float* bn1g   = (const float*)d_in[8];
  const float* bn1b   = (const float*)d_in[9];
  const float* W1     = (const float*)d_in[10];
  const float* b1     = (const float*)d_in[11];
  const float* W2     = (const float*)d_in[12];
  const float* b2     = (const float*)d_in[13];
  const float* bn2g   = (const float*)d_in[14];
  const float* bn2b   = (const float*)d_in[15];

  char* ws = (char*)d_ws;
  size_t o = 0;
  u16*    hbf    = (u16*)  (ws + o); o += alignup(16416ull*512*2);
  float*  hF     = (float*)(ws + o); o += alignup(16416ull*512*4);
  float*  bufB   = (float*)(ws + o); o += alignup(16416ull*512*4);   // also aliased as Vt
  u16*    heads  = (u16*)  (ws + o); o += alignup(16416ull*512*2);
  u16*    big    = (u16*)  (ws + o); o += alignup(16416ull*2048*2);  // union: xbf | qkv | ff
  u16*    winitT = (u16*)  (ws + o); o += alignup(512ull*256*2);
  u16*    wqkvT  = (u16*)  (ws + o); o += alignup(3ull*1536*512*2);
  u16*    woT    = (u16*)  (ws + o); o += alignup(3ull*512*512*2);
  u16*    w1T    = (u16*)  (ws + o); o += alignup(3ull*2048*512*2);
  u16*    w2T    = (u16*)  (ws + o); o += alignup(3ull*512*2048*2);
  float*  p1     = (float*)(ws + o); o += alignup(512ull*NB*4);
  float*  p2     = (float*)(ws + o); o += alignup(512ull*NB*4);
  float2* scv    = (float2*)(ws + o); o += alignup(512*8);
  u16* xbf = big; u16* qkv = big; u16* ffb = big;
  u16* VtB = (u16*)bufB;   // Vt lives in bufB: used only between vtrans and attn

  // input/weight conversion (re-done every call; inputs restored by harness)
  cvt_x_k<<<16384,256,0,stream>>>(x, xbf, 16384*256);
  trans_k<float><<<dim3(4,8,1),   256,0,stream>>>(W_init, winitT, 256, 512, 512, 256, 1, 131072, 0, 0, 0);
  trans_k<float><<<dim3(8,1,24),  256,0,stream>>>(Wq, wqkvT,            512, 64, 64, 512, 8, 262144, 32768, 786432, 32768);
  trans_k<float><<<dim3(8,1,24),  256,0,stream>>>(Wk, wqkvT + 262144,   512, 64, 64, 512, 8, 262144, 32768, 786432, 32768);
  trans_k<float><<<dim3(8,1,24),  256,0,stream>>>(Wv, wqkvT + 524288,   512, 64, 64, 512, 8, 262144, 32768, 786432, 32768);
  trans_k<float><<<dim3(1,8,24),  256,0,stream>>>(Wo, woT,  64, 512, 512, 512, 8, 262144, 32768, 262144, 64);
  trans_k<float><<<dim3(8,32,3),  256,0,stream>>>(W1, w1T,  512, 2048, 2048, 512, 1, 1048576, 0, 1048576, 0);
  trans_k<float><<<dim3(32,8,3),  256,0,stream>>>(W2, w2T,  2048, 512, 512, 2048, 1, 1048576, 0, 1048576, 0);

  // h = x@W_init + b_init (row remap b*513+n), append eot row
  gemm_k<true,false,false,true,true,true><<<dim3(128,4),256,0,stream>>>(
      xbf, winitT, b_init, nullptr, hF, hbf, 16384, 512, 256);
  eot_k<<<64,256,0,stream>>>(eot, hF, hbf);

  for (int l = 0; l < 3; ++l){
    // QKV projection -> [16416][1536]
    gemm_k<false,false,false,false,true,false><<<dim3(129,12),256,0,stream>>>(
        hbf, wqkvT + (size_t)l*1536*512, nullptr, nullptr, nullptr, qkv, 16416, 1536, 512);
    // V transpose: qkv V-part -> Vt [b*8+h][64][520]
    trans_k<u16><<<dim3(9,1,256),256,0,stream>>>(qkv + 1024, VtB, 513, 64, 1536, 520, 8, 787968, 64, 266240, 33280);
    // attention
    attn_k<<<dim3(9,32,8),256,0,stream>>>(qkv, VtB, heads);
    // out-proj + skip -> bufB (f32) [overwrites Vt region: attn already done]
    gemm_k<false,false,true,true,false,false><<<dim3(129,4),256,0,stream>>>(
        heads, woT + (size_t)l*512*512, nullptr, hF, bufB, nullptr, 16416, 512, 512);
    // BN1
    bn_stats_k<<<513,256,0,stream>>>(bufB, p1, p2);
    bn_fin_k  <<<2,256,0,stream>>>(p1, p2, bn1g + l*512, bn1b + l*512, scv);
    bn_apply_k<<<2048,256,0,stream>>>(bufB, scv, hF, hbf);
    // FFN
    gemm_k<true,true,false,false,true,false><<<dim3(129,16),256,0,stream>>>(
        hbf, w1T + (size_t)l*2048*512, b1 + l*2048, nullptr, nullptr, ffb, 16416, 2048, 512);
    gemm_k<true,false,true,true,false,false><<<dim3(129,4),256,0,stream>>>(
        ffb, w2T + (size_t)l*512*2048, b2 + l*512, hF, bufB, nullptr, 16416, 512, 2048);
    // BN2 (last layer writes final output)
    bn_stats_k<<<513,256,0,stream>>>(bufB, p1, p2);
    bn_fin_k  <<<2,256,0,stream>>>(p1, p2, bn2g + l*512, bn2b + l*512, scv);
    bn_apply_k<<<2048,256,0,stream>>>(bufB, scv, (l==2) ? (float*)d_out : hF, hbf);
  }
}

// Round 3
// 1274.059 us; speedup vs baseline: 1.6058x; 1.6058x over previous
//
#include <hip/hip_runtime.h>
#include <stdint.h>

typedef unsigned short u16;
typedef __attribute__((ext_vector_type(8))) short bfrag;   // 8 x bf16 (4 VGPR)
typedef __attribute__((ext_vector_type(4))) float f32x4;   // MFMA accumulator

#define MFMA16(a,b,c) __builtin_amdgcn_mfma_f32_16x16x32_bf16(a,b,c,0,0,0)

__device__ __forceinline__ u16 f2b(float f){
  union { float f; uint32_t u; } v; v.f = f;
  uint32_t r = v.u + 0x7FFFu + ((v.u >> 16) & 1u);   // RNE, finite-only
  return (u16)(r >> 16);
}
__device__ __forceinline__ u16 f2b_fast(float f){    // round-half-up (P only)
  union { float f; uint32_t u; } v; v.f = f;
  return (u16)((v.u + 0x8000u) >> 16);
}
__device__ __forceinline__ float b2f(u16 b){
  union { uint32_t u; float f; } v; v.u = ((uint32_t)b) << 16; return v.f;
}

typedef const __attribute__((address_space(1))) unsigned int* gas_t;
typedef __attribute__((address_space(3))) unsigned int* las_t;
__device__ __forceinline__ void async16(const u16* g, u16* l){
  __builtin_amdgcn_global_load_lds((gas_t)g, (las_t)l, 16, 0, 0);
}

// ---------------- elementwise conversions ----------------
__global__ __launch_bounds__(256) void cvt_x_k(const float* __restrict__ x, u16* __restrict__ o, int n){
  int i = blockIdx.x*256 + threadIdx.x;
  if (i < n) o[i] = f2b(x[i]);
}
__global__ __launch_bounds__(256) void eot_k(const float* __restrict__ eot, float* __restrict__ hF, u16* __restrict__ hbf){
  int i = blockIdx.x*256 + threadIdx.x;          // [32 b][512 d]
  int b = i >> 9, d = i & 511;
  float v = eot[d];
  size_t idx = ((size_t)b*513 + 512)*512 + d;
  hF[idx] = v; hbf[idx] = f2b(v);
}

// ---------------- tiled transpose + convert ----------------
// src slice: src + (s/div)*srcA + (s%div)*srcB, row stride SS, shape R x C (C%64==0)
// dst slice: dst + (s/div)*dstA + (s%div)*dstB, row stride DS; out[c][r] = src[r][c]
template<typename T>
__global__ __launch_bounds__(256) void trans_k(const T* __restrict__ src, u16* __restrict__ dst,
    int R, int C, int SS, int DS, int div, size_t srcA, size_t srcB, size_t dstA, size_t dstB)
{
  __shared__ u16 tile[64][72];
  int s = blockIdx.z;
  const T* sp = src + (size_t)(s/div)*srcA + (size_t)(s%div)*srcB;
  u16* dp = dst + (size_t)(s/div)*dstA + (size_t)(s%div)*dstB;
  int r0 = blockIdx.x*64, c0 = blockIdx.y*64;
  int t = threadIdx.x;
  int tr = t>>2, tc = (t&3)*16;
  int rr = r0+tr; if (rr >= R) rr = R-1;
  const T* p = sp + (size_t)rr*SS + c0 + tc;
  u16 bv[16];
  if constexpr (sizeof(T)==4) {
    float4 a = *(const float4*)p, b = *(const float4*)(p+4),
           c = *(const float4*)(p+8), d = *(const float4*)(p+12);
    float f[16] = {a.x,a.y,a.z,a.w,b.x,b.y,b.z,b.w,c.x,c.y,c.z,c.w,d.x,d.y,d.z,d.w};
    #pragma unroll
    for (int i=0;i<16;i++) bv[i] = f2b(f[i]);
  } else {
    *(uint4*)&bv[0] = ((const uint4*)p)[0];
    *(uint4*)&bv[8] = ((const uint4*)p)[1];
  }
  *(uint4*)&tile[tr][tc]   = *(uint4*)&bv[0];
  *(uint4*)&tile[tr][tc+8] = *(uint4*)&bv[8];
  __syncthreads();
  int oc = t>>2, orr = (t&3)*16;
  u16 ov[16];
  #pragma unroll
  for (int i=0;i<16;i++) ov[i] = tile[orr+i][oc];
  u16* q = dp + (size_t)(c0+oc)*DS + r0 + orr;
  if (r0 + 64 <= R) {
    *(uint4*)q     = *(uint4*)&ov[0];
    *(uint4*)(q+8) = *(uint4*)&ov[8];
  } else {
    #pragma unroll
    for (int i=0;i<16;i++){
      int rg = r0 + orr + i;
      if (rg < DS) q[i] = (rg < R) ? ov[i] : (u16)0;   // zero-fill pad cols (finite bf16)
    }
  }
}

// ---------------- GEMM: C[M,N] = A[M,K](bf16) * BT[N,K](bf16)^T, BK=64 ----------------
// LDS[row][ch] holds global chunk (ch ^ (row&7)); frag chunk c read at ch = c^(rr&7)
template<bool BIAS,bool RELU,bool SKIP,bool OUTF,bool OUTB,bool REMAP>
__global__ __launch_bounds__(256,2) void gemm_k(
    const u16* __restrict__ A, const u16* __restrict__ BT,
    const float* __restrict__ bias, const float* __restrict__ skip,
    float* __restrict__ outF, u16* __restrict__ outB,
    int M, int N, int K)
{
  __shared__ u16 Ash[128*64];
  __shared__ u16 Bsh[128*64];
  const int tid = threadIdx.x;
  const int lane = tid & 63, wv = tid >> 6;
  const int mt = blockIdx.x, nt = blockIdx.y;
  const int wrow = (wv >> 1) << 6, wcol = (wv & 1) << 6;
  const int g = lane >> 4, ci = lane & 15;

  f32x4 acc[4][4];
  #pragma unroll
  for (int i=0;i<4;i++)
    #pragma unroll
    for (int j=0;j<4;j++) acc[i][j] = (f32x4){0.f,0.f,0.f,0.f};

  int aofs[4][2], bofs[4][2];
  #pragma unroll
  for (int mi=0;mi<4;mi++){
    int rr = wrow + mi*16 + ci;
    int cc = wcol + mi*16 + ci;
    #pragma unroll
    for (int kh=0;kh<2;kh++){
      aofs[mi][kh] = rr*64 + ((((kh<<2)|g) ^ (rr&7))<<3);
      bofs[mi][kh] = cc*64 + ((((kh<<2)|g) ^ (cc&7))<<3);
    }
  }
  const u16* ga[4]; const u16* gb[4];
  #pragma unroll
  for (int q=0;q<4;q++){
    int row = q*32 + (tid>>3);
    int sc  = (tid&7) ^ (row&7);
    int arow = mt*128 + row; if (arow >= M) arow = M-1;
    int brow = nt*128 + row;
    ga[q] = A  + (size_t)arow*K + sc*8;
    gb[q] = BT + (size_t)brow*K + sc*8;
  }
  u16* la = Ash + tid*8;
  u16* lb = Bsh + tid*8;

  for (int kt = 0; kt < K; kt += 64){
    #pragma unroll
    for (int q=0;q<4;q++) async16(ga[q] + kt, la + q*2048);
    #pragma unroll
    for (int q=0;q<4;q++) async16(gb[q] + kt, lb + q*2048);
    __syncthreads();
    #pragma unroll
    for (int kh=0;kh<2;kh++){
      bfrag a[4], b[4];
      #pragma unroll
      for (int mi=0;mi<4;mi++) a[mi] = *(const bfrag*)&Ash[aofs[mi][kh]];
      #pragma unroll
      for (int ni=0;ni<4;ni++) b[ni] = *(const bfrag*)&Bsh[bofs[ni][kh]];
      #pragma unroll
      for (int mi=0;mi<4;mi++)
        #pragma unroll
        for (int ni=0;ni<4;ni++)
          acc[mi][ni] = MFMA16(a[mi], b[ni], acc[mi][ni]);
    }
    __syncthreads();
  }

  #pragma unroll
  for (int mi=0;mi<4;mi++){
    #pragma unroll
    for (int r=0;r<4;r++){
      int gm = mt*128 + wrow + mi*16 + g*4 + r;
      if (gm >= M) continue;
      size_t orow = REMAP ? (size_t)(gm + (gm >> 9)) : (size_t)gm;
      #pragma unroll
      for (int ni=0;ni<4;ni++){
        int gn = nt*128 + wcol + ni*16 + ci;
        float v = acc[mi][ni][r];
        if (BIAS) v += bias[gn];
        if (SKIP) v += skip[(size_t)gm*N + gn];
        if (RELU) v = fmaxf(v, 0.f);
        if (OUTF) outF[orow*N + gn] = v;
        if (OUTB) outB[orow*N + gn] = f2b(v);
      }
    }
  }
}

// ---------------- attention: 4 waves/block, wave = one 16-row q-tile, KVB=64 ----------------
// qkv rows [b*513+n][1536] = Q|K|V each h*64+d ; Vt [b*8+h][64 d][520 n] bf16
#define LOG2E_SC 0.1803368801f   /* 0.125 * log2(e) */
__global__ __launch_bounds__(256) void attn_k(const u16* __restrict__ qkv, const u16* __restrict__ Vt,
                                              u16* __restrict__ heads)
{
  __shared__ u16 P_lds[4][16*72];
  const int wv = threadIdx.x >> 6;
  const int qt = blockIdx.x*4 + wv;
  if (qt > 32) return;
  const int b = blockIdx.y, hh = blockIdx.z;
  const int lane = threadIdx.x & 63;
  const int g = lane >> 4, ci = lane & 15;
  u16* P_l = P_lds[wv];

  const size_t rowb = (size_t)b * 513;
  int q = qt*16 + ci; int qr = q < 513 ? q : 512;
  const u16* qp = qkv + (rowb + qr)*1536 + hh*64 + g*8;
  bfrag aq0 = *(const bfrag*)qp;
  bfrag aq1 = *(const bfrag*)(qp + 32);

  const u16* kbase = qkv + rowb*1536 + 512 + hh*64;
  const u16* vbase = Vt + (size_t)(b*8 + hh)*33280;

  f32x4 hacc[4];
  #pragma unroll
  for (int dt=0;dt<4;dt++) hacc[dt] = (f32x4){0.f,0.f,0.f,0.f};
  float mrun[4] = {-1e30f,-1e30f,-1e30f,-1e30f};
  float srun[4] = {0.f,0.f,0.f,0.f};

  for (int np = 0; np < 9; ++np){
    const int n0 = np*64;
    const bool tail = (np == 8);
    // K fragments (8 x b128 global)
    bfrag kf[4][2];
    #pragma unroll
    for (int t=0;t<4;t++){
      int n = n0 + t*16 + ci; if (n > 512) n = 512;
      const u16* kp = kbase + (size_t)n*1536;
      kf[t][0] = *(const bfrag*)(kp + g*8);
      kf[t][1] = *(const bfrag*)(kp + 32 + g*8);
    }
    // V fragments (8 x b128 global from Vt rows)
    bfrag vf[4][2];
    #pragma unroll
    for (int dt=0;dt<4;dt++){
      const u16* vr = vbase + (size_t)(dt*16 + ci)*520;
      #pragma unroll
      for (int kh=0;kh<2;kh++){
        int nv = tail ? 512 : (n0 + kh*32 + g*8);
        vf[dt][kh] = *(const bfrag*)(vr + nv);
      }
    }
    // S = Q K^T, scaled into log2 domain
    f32x4 s[4];
    #pragma unroll
    for (int t=0;t<4;t++){
      f32x4 z = (f32x4){0.f,0.f,0.f,0.f};
      z = MFMA16(aq0, kf[t][0], z);
      z = MFMA16(aq1, kf[t][1], z);
      #pragma unroll
      for (int r=0;r<4;r++) s[t][r] = z[r]*LOG2E_SC;
    }
    if (tail){
      #pragma unroll
      for (int t=0;t<4;t++){
        bool v = (n0 + t*16 + ci) < 513;
        #pragma unroll
        for (int r=0;r<4;r++) s[t][r] = v ? s[t][r] : -1e30f;
      }
    }
    // online softmax: row = g*4+r, reduce over n = t*16+ci
    float pm[4];
    #pragma unroll
    for (int r=0;r<4;r++)
      pm[r] = fmaxf(fmaxf(s[0][r],s[1][r]), fmaxf(s[2][r],s[3][r]));
    #pragma unroll
    for (int m=1;m<16;m<<=1)
      #pragma unroll
      for (int r=0;r<4;r++) pm[r] = fmaxf(pm[r], __shfl_xor(pm[r], m));
    float f[4];
    #pragma unroll
    for (int r=0;r<4;r++){
      float mn = fmaxf(mrun[r], pm[r]);
      f[r] = __builtin_exp2f(mrun[r] - mn);
      mrun[r] = mn;
      #pragma unroll
      for (int t=0;t<4;t++) s[t][r] = __builtin_exp2f(s[t][r] - mn);
    }
    float psum[4];
    #pragma unroll
    for (int r=0;r<4;r++) psum[r] = (s[0][r]+s[1][r]) + (s[2][r]+s[3][r]);
    #pragma unroll
    for (int m=1;m<16;m<<=1)
      #pragma unroll
      for (int r=0;r<4;r++) psum[r] += __shfl_xor(psum[r], m);
    #pragma unroll
    for (int r=0;r<4;r++) srun[r] = srun[r]*f[r] + psum[r];
    #pragma unroll
    for (int dt=0;dt<4;dt++){
      hacc[dt][0]*=f[0]; hacc[dt][1]*=f[1]; hacc[dt][2]*=f[2]; hacc[dt][3]*=f[3];
    }
    // P -> LDS (row q=g*4+r, col n-local = t*16+ci)
    #pragma unroll
    for (int r=0;r<4;r++)
      #pragma unroll
      for (int t=0;t<4;t++)
        P_l[(g*4+r)*72 + t*16 + ci] = f2b_fast(s[t][r]);
    // A-frag: row = ci, k = kh*32 + g*8 + j  (same-wave DS ordering; compiler inserts waits)
    bfrag pa0 = *(const bfrag*)&P_l[ci*72 + g*8];
    bfrag pa1 = *(const bfrag*)&P_l[ci*72 + 32 + g*8];
    #pragma unroll
    for (int dt=0;dt<4;dt++){
      hacc[dt] = MFMA16(pa0, vf[dt][0], hacc[dt]);
      hacc[dt] = MFMA16(pa1, vf[dt][1], hacc[dt]);
    }
  }
  float rs[4];
  #pragma unroll
  for (int r=0;r<4;r++) rs[r] = 1.0f / srun[r];
  #pragma unroll
  for (int dt=0;dt<4;dt++)
    #pragma unroll
    for (int r=0;r<4;r++){
      int qg = qt*16 + g*4 + r;
      if (qg < 513)
        heads[(rowb + qg)*512 + hh*64 + dt*16 + ci] = f2b(hacc[dt][r]*rs[r]);
    }
}

// ---------------- BatchNorm (train-mode, biased var) ----------------
#define NB 1026
__global__ __launch_bounds__(256) void bn_stats_k(const float* __restrict__ in, float* __restrict__ p1, float* __restrict__ p2){
  int blk = blockIdx.x, t = threadIdx.x;       // grid 513, rows blk*32..+31
  int c4 = t & 127, rh = t >> 7;
  float4 s = {0,0,0,0}, qq = {0,0,0,0};
  for (int i = rh; i < 32; i += 2){
    float4 v = ((const float4*)in)[(size_t)(blk*32 + i)*128 + c4];
    s.x += v.x; s.y += v.y; s.z += v.z; s.w += v.w;
    qq.x += v.x*v.x; qq.y += v.y*v.y; qq.z += v.z*v.z; qq.w += v.w*v.w;
  }
  size_t base = (size_t)(c4*4)*NB + blk*2 + rh;
  p1[base] = s.x; p1[base+NB] = s.y; p1[base+2*NB] = s.z; p1[base+3*NB] = s.w;
  p2[base] = qq.x; p2[base+NB] = qq.y; p2[base+2*NB] = qq.z; p2[base+3*NB] = qq.w;
}
// parallel finalize: one block per channel, coalesced partial reads + wave reduce
__global__ __launch_bounds__(256) void bn_fin_k(const float* __restrict__ p1, const float* __restrict__ p2,
                                               const float* __restrict__ gamma, const float* __restrict__ beta,
                                               float2* __restrict__ sc){
  const int c = blockIdx.x;         // 512 blocks
  const int t = threadIdx.x;
  float S = 0.f, Q = 0.f;
  for (int i = t; i < NB; i += 256){
    S += p1[(size_t)c*NB + i];
    Q += p2[(size_t)c*NB + i];
  }
  #pragma unroll
  for (int m = 1; m < 64; m <<= 1){
    S += __shfl_xor(S, m);
    Q += __shfl_xor(Q, m);
  }
  __shared__ float sS[4], sQ[4];
  int wv = t >> 6, lane = t & 63;
  if (lane == 0){ sS[wv] = S; sQ[wv] = Q; }
  __syncthreads();
  if (t == 0){
    float Sa = (sS[0]+sS[1]) + (sS[2]+sS[3]);
    float Qa = (sQ[0]+sQ[1]) + (sQ[2]+sQ[3]);
    const float invM = 1.0f/16416.0f;
    float mean = Sa*invM;
    float var  = Qa*invM - mean*mean;
    float scl  = gamma[c] * rsqrtf(var + 1e-5f);
    sc[c] = make_float2(scl, beta[c] - mean*scl);
  }
}
__global__ __launch_bounds__(256) void bn_apply_k(const float* __restrict__ in, const float2* __restrict__ sc,
                                                  float* __restrict__ outF, u16* __restrict__ outB){
  const int n4 = 16416*512/4;
  for (int i = blockIdx.x*256 + threadIdx.x; i < n4; i += gridDim.x*256){
    float4 v = ((const float4*)in)[i];
    int c0 = (i << 2) & 511;
    float2 a = sc[c0], b = sc[c0+1], c = sc[c0+2], d = sc[c0+3];
    v.x = v.x*a.x + a.y; v.y = v.y*b.x + b.y; v.z = v.z*c.x + c.y; v.w = v.w*d.x + d.y;
    ((float4*)outF)[i] = v;
    ushort4 u; u.x=f2b(v.x); u.y=f2b(v.y); u.z=f2b(v.z); u.w=f2b(v.w);
    ((ushort4*)outB)[i] = u;
  }
}

// ---------------- host launcher ----------------
static inline size_t alignup(size_t x){ return (x + 255) & ~(size_t)255; }

extern "C" void kernel_launch(void* const* d_in, const int* in_sizes, int n_in,
                              void* d_out, int out_size, void* d_ws, size_t ws_size,
                              hipStream_t stream)
{
  (void)in_sizes; (void)n_in; (void)out_size; (void)ws_size;
  const float* x      = (const float*)d_in[0];
  const float* W_init = (const float*)d_in[1];
  const float* b_init = (const float*)d_in[2];
  const float* eot    = (const float*)d_in[3];
  const float* Wq     = (const float*)d_in[4];
  const float* Wk     = (const float*)d_in[5];
  const float* Wv     = (const float*)d_in[6];
  const float* Wo     = (const float*)d_in[7];
  const float* bn1g   = (const float*)d_in[8];
  const float* bn1b   = (const float*)d_in[9];
  const float* W1     = (const float*)d_in[10];
  const float* b1     = (const float*)d_in[11];
  const float* W2     = (const float*)d_in[12];
  const float* b2     = (const float*)d_in[13];
  const float* bn2g   = (const float*)d_in[14];
  const float* bn2b   = (const float*)d_in[15];

  char* ws = (char*)d_ws;
  size_t o = 0;
  u16*    hbf    = (u16*)  (ws + o); o += alignup(16416ull*512*2);
  float*  hF     = (float*)(ws + o); o += alignup(16416ull*512*4);
  float*  bufB   = (float*)(ws + o); o += alignup(16416ull*512*4);   // also aliased as Vt
  u16*    heads  = (u16*)  (ws + o); o += alignup(16416ull*512*2);
  u16*    big    = (u16*)  (ws + o); o += alignup(16416ull*2048*2);  // union: xbf | qkv | ff
  u16*    winitT = (u16*)  (ws + o); o += alignup(512ull*256*2);
  u16*    wqkvT  = (u16*)  (ws + o); o += alignup(3ull*1536*512*2);
  u16*    woT    = (u16*)  (ws + o); o += alignup(3ull*512*512*2);
  u16*    w1T    = (u16*)  (ws + o); o += alignup(3ull*2048*512*2);
  u16*    w2T    = (u16*)  (ws + o); o += alignup(3ull*512*2048*2);
  float*  p1     = (float*)(ws + o); o += alignup(512ull*NB*4);
  float*  p2     = (float*)(ws + o); o += alignup(512ull*NB*4);
  float2* scv    = (float2*)(ws + o); o += alignup(512*8);
  u16* xbf = big; u16* qkv = big; u16* ffb = big;
  u16* VtB = (u16*)bufB;   // Vt lives in bufB: used only between vtrans and attn

  // input/weight conversion (re-done every call; inputs restored by harness)
  cvt_x_k<<<16384,256,0,stream>>>(x, xbf, 16384*256);
  trans_k<float><<<dim3(4,8,1),   256,0,stream>>>(W_init, winitT, 256, 512, 512, 256, 1, 131072, 0, 0, 0);
  trans_k<float><<<dim3(8,1,24),  256,0,stream>>>(Wq, wqkvT,            512, 64, 64, 512, 8, 262144, 32768, 786432, 32768);
  trans_k<float><<<dim3(8,1,24),  256,0,stream>>>(Wk, wqkvT + 262144,   512, 64, 64, 512, 8, 262144, 32768, 786432, 32768);
  trans_k<float><<<dim3(8,1,24),  256,0,stream>>>(Wv, wqkvT + 524288,   512, 64, 64, 512, 8, 262144, 32768, 786432, 32768);
  trans_k<float><<<dim3(1,8,24),  256,0,stream>>>(Wo, woT,  64, 512, 512, 512, 8, 262144, 32768, 262144, 64);
  trans_k<float><<<dim3(8,32,3),  256,0,stream>>>(W1, w1T,  512, 2048, 2048, 512, 1, 1048576, 0, 1048576, 0);
  trans_k<float><<<dim3(32,8,3),  256,0,stream>>>(W2, w2T,  2048, 512, 512, 2048, 1, 1048576, 0, 1048576, 0);

  // h = x@W_init + b_init (row remap b*513+n), append eot row
  gemm_k<true,false,false,true,true,true><<<dim3(128,4),256,0,stream>>>(
      xbf, winitT, b_init, nullptr, hF, hbf, 16384, 512, 256);
  eot_k<<<64,256,0,stream>>>(eot, hF, hbf);

  for (int l = 0; l < 3; ++l){
    // QKV projection -> [16416][1536]
    gemm_k<false,false,false,false,true,false><<<dim3(129,12),256,0,stream>>>(
        hbf, wqkvT + (size_t)l*1536*512, nullptr, nullptr, nullptr, qkv, 16416, 1536, 512);
    // V transpose: qkv V-part -> Vt [b*8+h][64][520]
    trans_k<u16><<<dim3(9,1,256),256,0,stream>>>(qkv + 1024, VtB, 513, 64, 1536, 520, 8, 787968, 64, 266240, 33280);
    // attention
    attn_k<<<dim3(9,32,8),256,0,stream>>>(qkv, VtB, heads);
    // out-proj + skip -> bufB (f32) [overwrites Vt region: attn already done]
    gemm_k<false,false,true,true,false,false><<<dim3(129,4),256,0,stream>>>(
        heads, woT + (size_t)l*512*512, nullptr, hF, bufB, nullptr, 16416, 512, 512);
    // BN1
    bn_stats_k<<<513,256,0,stream>>>(bufB, p1, p2);
    bn_fin_k  <<<512,256,0,stream>>>(p1, p2, bn1g + l*512, bn1b + l*512, scv);
    bn_apply_k<<<2048,256,0,stream>>>(bufB, scv, hF, hbf);
    // FFN
    gemm_k<true,true,false,false,true,false><<<dim3(129,16),256,0,stream>>>(
        hbf, w1T + (size_t)l*2048*512, b1 + l*2048, nullptr, nullptr, ffb, 16416, 2048, 512);
    gemm_k<true,false,true,true,false,false><<<dim3(129,4),256,0,stream>>>(
        ffb, w2T + (size_t)l*512*2048, b2 + l*512, hF, bufB, nullptr, 16416, 512, 2048);
    // BN2 (last layer writes final output)
    bn_stats_k<<<513,256,0,stream>>>(bufB, p1, p2);
    bn_fin_k  <<<512,256,0,stream>>>(p1, p2, bn2g + l*512, bn2b + l*512, scv);
    bn_apply_k<<<2048,256,0,stream>>>(bufB, scv, (l==2) ? (float*)d_out : hF, hbf);
  }
}

// Round 5
// 1266.177 us; speedup vs baseline: 1.6158x; 1.0062x over previous
//
#include <hip/hip_runtime.h>
#include <stdint.h>

typedef unsigned short u16;
typedef __attribute__((ext_vector_type(8))) short bfrag;   // 8 x bf16 (4 VGPR)
typedef __attribute__((ext_vector_type(4))) float f32x4;   // MFMA accumulator

#define MFMA16(a,b,c) __builtin_amdgcn_mfma_f32_16x16x32_bf16(a,b,c,0,0,0)

__device__ __forceinline__ u16 f2b(float f){
  union { float f; uint32_t u; } v; v.f = f;
  uint32_t r = v.u + 0x7FFFu + ((v.u >> 16) & 1u);   // RNE, finite-only
  return (u16)(r >> 16);
}
__device__ __forceinline__ uint32_t cvtpk(float lo, float hi){  // 2xf32 -> packed 2xbf16 (RNE)
  uint32_t r; asm("v_cvt_pk_bf16_f32 %0, %1, %2" : "=v"(r) : "v"(lo), "v"(hi)); return r;
}

typedef const __attribute__((address_space(1))) unsigned int* gas_t;
typedef __attribute__((address_space(3))) unsigned int* las_t;
__device__ __forceinline__ void async16(const u16* g, u16* l){
  __builtin_amdgcn_global_load_lds((gas_t)g, (las_t)l, 16, 0, 0);
}

// ---------------- elementwise conversions ----------------
__global__ __launch_bounds__(256) void cvt_x_k(const float* __restrict__ x, u16* __restrict__ o, int n){
  int i = blockIdx.x*256 + threadIdx.x;
  if (i < n) o[i] = f2b(x[i]);
}
__global__ __launch_bounds__(256) void eot_k(const float* __restrict__ eot, float* __restrict__ hF, u16* __restrict__ hbf){
  int i = blockIdx.x*256 + threadIdx.x;          // [32 b][512 d]
  int b = i >> 9, d = i & 511;
  float v = eot[d];
  size_t idx = ((size_t)b*513 + 512)*512 + d;
  hF[idx] = v; hbf[idx] = f2b(v);
}

// ---------------- tiled transpose + convert ----------------
template<typename T>
__global__ __launch_bounds__(256) void trans_k(const T* __restrict__ src, u16* __restrict__ dst,
    int R, int C, int SS, int DS, int div, size_t srcA, size_t srcB, size_t dstA, size_t dstB)
{
  __shared__ u16 tile[64][72];
  int s = blockIdx.z;
  const T* sp = src + (size_t)(s/div)*srcA + (size_t)(s%div)*srcB;
  u16* dp = dst + (size_t)(s/div)*dstA + (size_t)(s%div)*dstB;
  int r0 = blockIdx.x*64, c0 = blockIdx.y*64;
  int t = threadIdx.x;
  int tr = t>>2, tc = (t&3)*16;
  int rr = r0+tr; if (rr >= R) rr = R-1;
  const T* p = sp + (size_t)rr*SS + c0 + tc;
  u16 bv[16];
  if constexpr (sizeof(T)==4) {
    float4 a = *(const float4*)p, b = *(const float4*)(p+4),
           c = *(const float4*)(p+8), d = *(const float4*)(p+12);
    float f[16] = {a.x,a.y,a.z,a.w,b.x,b.y,b.z,b.w,c.x,c.y,c.z,c.w,d.x,d.y,d.z,d.w};
    #pragma unroll
    for (int i=0;i<16;i++) bv[i] = f2b(f[i]);
  } else {
    *(uint4*)&bv[0] = ((const uint4*)p)[0];
    *(uint4*)&bv[8] = ((const uint4*)p)[1];
  }
  *(uint4*)&tile[tr][tc]   = *(uint4*)&bv[0];
  *(uint4*)&tile[tr][tc+8] = *(uint4*)&bv[8];
  __syncthreads();
  int oc = t>>2, orr = (t&3)*16;
  u16 ov[16];
  #pragma unroll
  for (int i=0;i<16;i++) ov[i] = tile[orr+i][oc];
  u16* q = dp + (size_t)(c0+oc)*DS + r0 + orr;
  if (r0 + 64 <= R) {
    *(uint4*)q     = *(uint4*)&ov[0];
    *(uint4*)(q+8) = *(uint4*)&ov[8];
  } else {
    #pragma unroll
    for (int i=0;i<16;i++){
      int rg = r0 + orr + i;
      if (rg < DS) q[i] = (rg < R) ? ov[i] : (u16)0;   // zero-fill pad cols (finite bf16)
    }
  }
}

// ---------------- GEMM: C[M,N] = A[M,K](bf16) * BT[N,K](bf16)^T, BK=64 ----------------
template<bool BIAS,bool RELU,bool SKIP,bool OUTF,bool OUTB,bool REMAP>
__global__ __launch_bounds__(256,2) void gemm_k(
    const u16* __restrict__ A, const u16* __restrict__ BT,
    const float* __restrict__ bias, const float* __restrict__ skip,
    float* __restrict__ outF, u16* __restrict__ outB,
    int M, int N, int K)
{
  __shared__ u16 Ash[128*64];
  __shared__ u16 Bsh[128*64];
  const int tid = threadIdx.x;
  const int lane = tid & 63, wv = tid >> 6;
  const int mt = blockIdx.x, nt = blockIdx.y;
  const int wrow = (wv >> 1) << 6, wcol = (wv & 1) << 6;
  const int g = lane >> 4, ci = lane & 15;

  f32x4 acc[4][4];
  #pragma unroll
  for (int i=0;i<4;i++)
    #pragma unroll
    for (int j=0;j<4;j++) acc[i][j] = (f32x4){0.f,0.f,0.f,0.f};

  int aofs[4][2], bofs[4][2];
  #pragma unroll
  for (int mi=0;mi<4;mi++){
    int rr = wrow + mi*16 + ci;
    int cc = wcol + mi*16 + ci;
    #pragma unroll
    for (int kh=0;kh<2;kh++){
      aofs[mi][kh] = rr*64 + ((((kh<<2)|g) ^ (rr&7))<<3);
      bofs[mi][kh] = cc*64 + ((((kh<<2)|g) ^ (cc&7))<<3);
    }
  }
  const u16* ga[4]; const u16* gb[4];
  #pragma unroll
  for (int q=0;q<4;q++){
    int row = q*32 + (tid>>3);
    int sc  = (tid&7) ^ (row&7);
    int arow = mt*128 + row; if (arow >= M) arow = M-1;
    int brow = nt*128 + row;
    ga[q] = A  + (size_t)arow*K + sc*8;
    gb[q] = BT + (size_t)brow*K + sc*8;
  }
  u16* la = Ash + tid*8;
  u16* lb = Bsh + tid*8;

  for (int kt = 0; kt < K; kt += 64){
    #pragma unroll
    for (int q=0;q<4;q++) async16(ga[q] + kt, la + q*2048);
    #pragma unroll
    for (int q=0;q<4;q++) async16(gb[q] + kt, lb + q*2048);
    __syncthreads();
    #pragma unroll
    for (int kh=0;kh<2;kh++){
      bfrag a[4], b[4];
      #pragma unroll
      for (int mi=0;mi<4;mi++) a[mi] = *(const bfrag*)&Ash[aofs[mi][kh]];
      #pragma unroll
      for (int ni=0;ni<4;ni++) b[ni] = *(const bfrag*)&Bsh[bofs[ni][kh]];
      #pragma unroll
      for (int mi=0;mi<4;mi++)
        #pragma unroll
        for (int ni=0;ni<4;ni++)
          acc[mi][ni] = MFMA16(a[mi], b[ni], acc[mi][ni]);
    }
    __syncthreads();
  }

  #pragma unroll
  for (int mi=0;mi<4;mi++){
    #pragma unroll
    for (int r=0;r<4;r++){
      int gm = mt*128 + wrow + mi*16 + g*4 + r;
      if (gm >= M) continue;
      size_t orow = REMAP ? (size_t)(gm + (gm >> 9)) : (size_t)gm;
      #pragma unroll
      for (int ni=0;ni<4;ni++){
        int gn = nt*128 + wcol + ni*16 + ci;
        float v = acc[mi][ni][r];
        if (BIAS) v += bias[gn];
        if (SKIP) v += skip[(size_t)gm*N + gn];
        if (RELU) v = fmaxf(v, 0.f);
        if (OUTF) outF[orow*N + gn] = v;
        if (OUTB) outB[orow*N + gn] = f2b(v);
      }
    }
  }
}

// ---------------- attention: transposed-S flash, 4 waves/block, wave = 16 q-rows ----------------
// qkv rows [b*513+n][1536] = Q|K|V each h*64+d ; Vt [b*8+h][64 d][520 n] bf16
// S^T = mfma(K,Q): lane(ci,g) reg r holds S[q=ci][key=n0+t*16+g*4+r] -> softmax lane-local + 2 shfl.
// P routed via per-wave LDS row q=ci (4x ds_write_b64), PV B-frag read back as 2x ds_read_b128.
#define LOG2E_SC 0.1803368801f   /* 0.125 * log2(e) */
__global__ __launch_bounds__(256) void attn_k(const u16* __restrict__ qkv, const u16* __restrict__ Vt,
                                              u16* __restrict__ heads)
{
  __shared__ u16 P_lds[4][16*72];
  const int wv = threadIdx.x >> 6;
  const int qt = blockIdx.x*4 + wv;
  if (qt > 32) return;
  const int b = blockIdx.y, hh = blockIdx.z;
  const int lane = threadIdx.x & 63;
  const int g = lane >> 4, ci = lane & 15;
  u16* P_l = P_lds[wv];

  const size_t rowb = (size_t)b * 513;
  int q = qt*16 + ci; int qr = q < 513 ? q : 512;
  const u16* qp = qkv + (rowb + qr)*1536 + hh*64 + g*8;
  bfrag aq0 = *(const bfrag*)qp;               // B-frag: col=q(ci), k=d(g*8+j)
  bfrag aq1 = *(const bfrag*)(qp + 32);

  const u16* kbase = qkv + rowb*1536 + 512 + hh*64;
  const u16* vbase = Vt + (size_t)(b*8 + hh)*33280;

  f32x4 hacc[4];
  #pragma unroll
  for (int dt=0;dt<4;dt++) hacc[dt] = (f32x4){0.f,0.f,0.f,0.f};
  float mrun = -1e30f, srun = 0.f;

  for (int np = 0; np < 9; ++np){
    const int n0 = np*64;
    const bool tail = (np == 8);
    // S^T = K * Q : p_[t][r] = S[q=ci][key = n0+t*16+g*4+r]
    float p_[4][4];
    #pragma unroll
    for (int t=0;t<4;t++){
      int n = n0 + t*16 + ci; if (n > 512) n = 512;
      const u16* kp = kbase + (size_t)n*1536;
      bfrag k0 = *(const bfrag*)(kp + g*8);
      bfrag k1 = *(const bfrag*)(kp + 32 + g*8);
      f32x4 z = (f32x4){0.f,0.f,0.f,0.f};
      z = MFMA16(k0, aq0, z);
      z = MFMA16(k1, aq1, z);
      #pragma unroll
      for (int r=0;r<4;r++) p_[t][r] = z[r]*LOG2E_SC;
    }
    if (tail){
      #pragma unroll
      for (int t=0;t<4;t++)
        #pragma unroll
        for (int r=0;r<4;r++)
          if (n0 + t*16 + g*4 + r >= 513) p_[t][r] = -1e30f;
    }
    // V fragments (A-operand of PV): row d = dt*16+ci, k = key = n0+kh*32+g*8+j
    bfrag vf[4][2];
    #pragma unroll
    for (int dt=0;dt<4;dt++){
      const u16* vr = vbase + (size_t)(dt*16 + ci)*520;
      #pragma unroll
      for (int kh=0;kh<2;kh++){
        int nv = tail ? 512 : (n0 + kh*32 + g*8);
        vf[dt][kh] = *(const bfrag*)(vr + nv);
      }
    }
    // per-q softmax: 16 in-lane values + 2 shfl steps (across g)
    float pm = p_[0][0];
    #pragma unroll
    for (int t=0;t<4;t++)
      #pragma unroll
      for (int r=0;r<4;r++) pm = fmaxf(pm, p_[t][r]);
    pm = fmaxf(pm, __shfl_xor(pm, 16));
    pm = fmaxf(pm, __shfl_xor(pm, 32));
    float mn = fmaxf(mrun, pm);
    float f = __builtin_exp2f(mrun - mn);
    mrun = mn;
    float ps = 0.f;
    #pragma unroll
    for (int t=0;t<4;t++)
      #pragma unroll
      for (int r=0;r<4;r++){ p_[t][r] = __builtin_exp2f(p_[t][r] - mn); ps += p_[t][r]; }
    ps += __shfl_xor(ps, 16);
    ps += __shfl_xor(ps, 32);
    srun = srun*f + ps;
    #pragma unroll
    for (int dt=0;dt<4;dt++){
      hacc[dt][0]*=f; hacc[dt][1]*=f; hacc[dt][2]*=f; hacc[dt][3]*=f;
    }
    // P -> LDS: row q=ci, keys t*16+g*4+(0..3) as one b64 per t
    #pragma unroll
    for (int t=0;t<4;t++){
      uint2 w2; w2.x = cvtpk(p_[t][0], p_[t][1]); w2.y = cvtpk(p_[t][2], p_[t][3]);
      *(uint2*)&P_l[ci*72 + t*16 + g*4] = w2;
    }
    // B-frag read-back: col=q(ci), k = kh*32+g*8+j (same-wave DS ordering)
    bfrag pb0 = *(const bfrag*)&P_l[ci*72 + g*8];
    bfrag pb1 = *(const bfrag*)&P_l[ci*72 + 32 + g*8];
    #pragma unroll
    for (int dt=0;dt<4;dt++){
      hacc[dt] = MFMA16(vf[dt][0], pb0, hacc[dt]);
      hacc[dt] = MFMA16(vf[dt][1], pb1, hacc[dt]);
    }
  }
  // O^T (lane holds O[q=ci][d=dt*16+g*4+r]) -> LDS row q -> coalesced b128 store
  float rs = 1.0f / srun;
  #pragma unroll
  for (int dt=0;dt<4;dt++)
    #pragma unroll
    for (int r=0;r<4;r++)
      P_l[ci*72 + dt*16 + g*4 + r] = f2b(hacc[dt][r]*rs);
  bfrag o0 = *(const bfrag*)&P_l[ci*72 + g*8];
  bfrag o1 = *(const bfrag*)&P_l[ci*72 + 32 + g*8];
  if (qt*16 + ci < 513){
    u16* hp = heads + (rowb + qt*16 + ci)*512 + hh*64 + g*8;
    *(bfrag*)hp = o0;
    *(bfrag*)(hp + 32) = o1;
  }
}

// ---------------- BatchNorm (train-mode, biased var) ----------------
#define NB 1026
__global__ __launch_bounds__(256) void bn_stats_k(const float* __restrict__ in, float* __restrict__ p1, float* __restrict__ p2){
  int blk = blockIdx.x, t = threadIdx.x;       // grid 513, rows blk*32..+31
  int c4 = t & 127, rh = t >> 7;
  float4 s = {0,0,0,0}, qq = {0,0,0,0};
  for (int i = rh; i < 32; i += 2){
    float4 v = ((const float4*)in)[(size_t)(blk*32 + i)*128 + c4];
    s.x += v.x; s.y += v.y; s.z += v.z; s.w += v.w;
    qq.x += v.x*v.x; qq.y += v.y*v.y; qq.z += v.z*v.z; qq.w += v.w*v.w;
  }
  size_t base = (size_t)(c4*4)*NB + blk*2 + rh;
  p1[base] = s.x; p1[base+NB] = s.y; p1[base+2*NB] = s.z; p1[base+3*NB] = s.w;
  p2[base] = qq.x; p2[base+NB] = qq.y; p2[base+2*NB] = qq.z; p2[base+3*NB] = qq.w;
}
__global__ __launch_bounds__(256) void bn_fin_k(const float* __restrict__ p1, const float* __restrict__ p2,
                                               const float* __restrict__ gamma, const float* __restrict__ beta,
                                               float2* __restrict__ sc){
  const int c = blockIdx.x;         // 512 blocks
  const int t = threadIdx.x;
  float S = 0.f, Q = 0.f;
  for (int i = t; i < NB; i += 256){
    S += p1[(size_t)c*NB + i];
    Q += p2[(size_t)c*NB + i];
  }
  #pragma unroll
  for (int m = 1; m < 64; m <<= 1){
    S += __shfl_xor(S, m);
    Q += __shfl_xor(Q, m);
  }
  __shared__ float sS[4], sQ[4];
  int wv = t >> 6, lane = t & 63;
  if (lane == 0){ sS[wv] = S; sQ[wv] = Q; }
  __syncthreads();
  if (t == 0){
    float Sa = (sS[0]+sS[1]) + (sS[2]+sS[3]);
    float Qa = (sQ[0]+sQ[1]) + (sQ[2]+sQ[3]);
    const float invM = 1.0f/16416.0f;
    float mean = Sa*invM;
    float var  = Qa*invM - mean*mean;
    float scl  = gamma[c] * rsqrtf(var + 1e-5f);
    sc[c] = make_float2(scl, beta[c] - mean*scl);
  }
}
__global__ __launch_bounds__(256) void bn_apply_k(const float* __restrict__ in, const float2* __restrict__ sc,
                                                  float* __restrict__ outF, u16* __restrict__ outB){
  const int n4 = 16416*512/4;
  for (int i = blockIdx.x*256 + threadIdx.x; i < n4; i += gridDim.x*256){
    float4 v = ((const float4*)in)[i];
    int c0 = (i << 2) & 511;
    float2 a = sc[c0], b = sc[c0+1], c = sc[c0+2], d = sc[c0+3];
    v.x = v.x*a.x + a.y; v.y = v.y*b.x + b.y; v.z = v.z*c.x + c.y; v.w = v.w*d.x + d.y;
    ((float4*)outF)[i] = v;
    ushort4 u; u.x=f2b(v.x); u.y=f2b(v.y); u.z=f2b(v.z); u.w=f2b(v.w);
    ((ushort4*)outB)[i] = u;
  }
}

// ---------------- host launcher ----------------
static inline size_t alignup(size_t x){ return (x + 255) & ~(size_t)255; }

extern "C" void kernel_launch(void* const* d_in, const int* in_sizes, int n_in,
                              void* d_out, int out_size, void* d_ws, size_t ws_size,
                              hipStream_t stream)
{
  (void)in_sizes; (void)n_in; (void)out_size; (void)ws_size;
  const float* x      = (const float*)d_in[0];
  const float* W_init = (const float*)d_in[1];
  const float* b_init = (const float*)d_in[2];
  const float* eot    = (const float*)d_in[3];
  const float* Wq     = (const float*)d_in[4];
  const float* Wk     = (const float*)d_in[5];
  const float* Wv     = (const float*)d_in[6];
  const float* Wo     = (const float*)d_in[7];
  const float* bn1g   = (const float*)d_in[8];
  const float* bn1b   = (const float*)d_in[9];
  const float* W1     = (const float*)d_in[10];
  const float* b1     = (const float*)d_in[11];
  const float* W2     = (const float*)d_in[12];
  const float* b2     = (const float*)d_in[13];
  const float* bn2g   = (const float*)d_in[14];
  const float* bn2b   = (const float*)d_in[15];

  char* ws = (char*)d_ws;
  size_t o = 0;
  u16*    hbf    = (u16*)  (ws + o); o += alignup(16416ull*512*2);
  float*  hF     = (float*)(ws + o); o += alignup(16416ull*512*4);
  float*  bufB   = (float*)(ws + o); o += alignup(16416ull*512*4);   // also aliased as Vt
  u16*    heads  = (u16*)  (ws + o); o += alignup(16416ull*512*2);
  u16*    big    = (u16*)  (ws + o); o += alignup(16416ull*2048*2);  // union: xbf | qkv | ff
  u16*    winitT = (u16*)  (ws + o); o += alignup(512ull*256*2);
  u16*    wqkvT  = (u16*)  (ws + o); o += alignup(3ull*1536*512*2);
  u16*    woT    = (u16*)  (ws + o); o += alignup(3ull*512*512*2);
  u16*    w1T    = (u16*)  (ws + o); o += alignup(3ull*2048*512*2);
  u16*    w2T    = (u16*)  (ws + o); o += alignup(3ull*512*2048*2);
  float*  p1     = (float*)(ws + o); o += alignup(512ull*NB*4);
  float*  p2     = (float*)(ws + o); o += alignup(512ull*NB*4);
  float2* scv    = (float2*)(ws + o); o += alignup(512*8);
  u16* xbf = big; u16* qkv = big; u16* ffb = big;
  u16* VtB = (u16*)bufB;   // Vt lives in bufB: used only between vtrans and attn

  // input/weight conversion (re-done every call; inputs restored by harness)
  cvt_x_k<<<16384,256,0,stream>>>(x, xbf, 16384*256);
  trans_k<float><<<dim3(4,8,1),   256,0,stream>>>(W_init, winitT, 256, 512, 512, 256, 1, 131072, 0, 0, 0);
  trans_k<float><<<dim3(8,1,24),  256,0,stream>>>(Wq, wqkvT,            512, 64, 64, 512, 8, 262144, 32768, 786432, 32768);
  trans_k<float><<<dim3(8,1,24),  256,0,stream>>>(Wk, wqkvT + 262144,   512, 64, 64, 512, 8, 262144, 32768, 786432, 32768);
  trans_k<float><<<dim3(8,1,24),  256,0,stream>>>(Wv, wqkvT + 524288,   512, 64, 64, 512, 8, 262144, 32768, 786432, 32768);
  trans_k<float><<<dim3(1,8,24),  256,0,stream>>>(Wo, woT,  64, 512, 512, 512, 8, 262144, 32768, 262144, 64);
  trans_k<float><<<dim3(8,32,3),  256,0,stream>>>(W1, w1T,  512, 2048, 2048, 512, 1, 1048576, 0, 1048576, 0);
  trans_k<float><<<dim3(32,8,3),  256,0,stream>>>(W2, w2T,  2048, 512, 512, 2048, 1, 1048576, 0, 1048576, 0);

  // h = x@W_init + b_init (row remap b*513+n), append eot row
  gemm_k<true,false,false,true,true,true><<<dim3(128,4),256,0,stream>>>(
      xbf, winitT, b_init, nullptr, hF, hbf, 16384, 512, 256);
  eot_k<<<64,256,0,stream>>>(eot, hF, hbf);

  for (int l = 0; l < 3; ++l){
    // QKV projection -> [16416][1536]
    gemm_k<false,false,false,false,true,false><<<dim3(129,12),256,0,stream>>>(
        hbf, wqkvT + (size_t)l*1536*512, nullptr, nullptr, nullptr, qkv, 16416, 1536, 512);
    // V transpose: qkv V-part -> Vt [b*8+h][64][520]
    trans_k<u16><<<dim3(9,1,256),256,0,stream>>>(qkv + 1024, VtB, 513, 64, 1536, 520, 8, 787968, 64, 266240, 33280);
    // attention
    attn_k<<<dim3(9,32,8),256,0,stream>>>(qkv, VtB, heads);
    // out-proj + skip -> bufB (f32) [overwrites Vt region: attn already done]
    gemm_k<false,false,true,true,false,false><<<dim3(129,4),256,0,stream>>>(
        heads, woT + (size_t)l*512*512, nullptr, hF, bufB, nullptr, 16416, 512, 512);
    // BN1
    bn_stats_k<<<513,256,0,stream>>>(bufB, p1, p2);
    bn_fin_k  <<<512,256,0,stream>>>(p1, p2, bn1g + l*512, bn1b + l*512, scv);
    bn_apply_k<<<2048,256,0,stream>>>(bufB, scv, hF, hbf);
    // FFN
    gemm_k<true,true,false,false,true,false><<<dim3(129,16),256,0,stream>>>(
        hbf, w1T + (size_t)l*2048*512, b1 + l*2048, nullptr, nullptr, ffb, 16416, 2048, 512);
    gemm_k<true,false,true,true,false,false><<<dim3(129,4),256,0,stream>>>(
        ffb, w2T + (size_t)l*512*2048, b2 + l*512, hF, bufB, nullptr, 16416, 512, 2048);
    // BN2 (last layer writes final output)
    bn_stats_k<<<513,256,0,stream>>>(bufB, p1, p2);
    bn_fin_k  <<<512,256,0,stream>>>(p1, p2, bn2g + l*512, bn2b + l*512, scv);
    bn_apply_k<<<2048,256,0,stream>>>(bufB, scv, (l==2) ? (float*)d_out : hF, hbf);
  }
}